// Round 1
// baseline (285.718 us; speedup 1.0000x reference)
//
#include <hip/hip_runtime.h>
#include <hip/hip_bf16.h>

#define B_ 2
#define N_ 1024
#define T_ 4096
#define H_ 256
// E=2, D=2, K=9

// ---------------- depthwise conv1d (K=9, SAME, groups=N) ----------------
__global__ __launch_bounds__(256) void dwconv_kernel(
    const float* __restrict__ x, const float* __restrict__ w,
    const float* __restrict__ bias, float* __restrict__ h0) {
  __shared__ float xs[264];
  const int t0 = blockIdx.x * 256;
  const int n = blockIdx.y;
  const int b = blockIdx.z;
  const long row = (long)(b * N_ + n) * T_;
  const int tid = threadIdx.x;
  int t = t0 - 4 + tid;
  xs[tid] = (t >= 0 && t < T_) ? x[row + t] : 0.f;
  if (tid < 8) {
    int t2 = t0 + 252 + tid;
    xs[256 + tid] = (t2 < T_) ? x[row + t2] : 0.f;
  }
  __syncthreads();
  float acc = bias[n];
  #pragma unroll
  for (int k = 0; k < 9; ++k) acc += xs[tid + k] * w[n * 9 + k];
  h0[row + t0 + tid] = acc;
}

// ---------------- fp32 tiled GEMM: C[b] = relu(A @ Bm[b] + bias) ----------------
// A: [M,K] row-major, Bm: [batch,K,Nt], C: [batch,M,Nt]
#define BM 64
#define BN 128
#define BK 16
__global__ __launch_bounds__(256) void gemm_bias_relu(
    const float* __restrict__ A, const float* __restrict__ Bm,
    const float* __restrict__ bias, float* __restrict__ C,
    int M, int K, int Nt) {
  __shared__ float As[BK][BM + 4];
  __shared__ float Bs[BK][BN];
  const int tid = threadIdx.x;
  const int tx = tid & 15;   // n-group (TN=8)
  const int ty = tid >> 4;   // m-group (TM=4)
  const int n0 = blockIdx.x * BN;
  const int m0 = blockIdx.y * BM;
  const long boff = (long)blockIdx.z * K * Nt;
  const long coff = (long)blockIdx.z * M * Nt;

  float acc[4][8];
  #pragma unroll
  for (int i = 0; i < 4; ++i)
    #pragma unroll
    for (int j = 0; j < 8; ++j) acc[i][j] = 0.f;

  const int am = tid >> 2;         // 0..63
  const int ak4 = (tid & 3) * 4;   // 0,4,8,12

  for (int k0 = 0; k0 < K; k0 += BK) {
    float4 av = *(const float4*)&A[(long)(m0 + am) * K + k0 + ak4];
    As[ak4 + 0][am] = av.x;
    As[ak4 + 1][am] = av.y;
    As[ak4 + 2][am] = av.z;
    As[ak4 + 3][am] = av.w;
    #pragma unroll
    for (int j = 0; j < 2; ++j) {
      int slot = tid + j * 256;
      int bk = slot >> 5;
      int bn4 = (slot & 31) * 4;
      *(float4*)&Bs[bk][bn4] =
          *(const float4*)&Bm[boff + (long)(k0 + bk) * Nt + n0 + bn4];
    }
    __syncthreads();
    #pragma unroll
    for (int k = 0; k < BK; ++k) {
      const float4 a = *(const float4*)&As[k][ty * 4];
      const float4 bb0 = *(const float4*)&Bs[k][tx * 8];
      const float4 bb1 = *(const float4*)&Bs[k][tx * 8 + 4];
      const float ar[4] = {a.x, a.y, a.z, a.w};
      const float br[8] = {bb0.x, bb0.y, bb0.z, bb0.w, bb1.x, bb1.y, bb1.z, bb1.w};
      #pragma unroll
      for (int i = 0; i < 4; ++i)
        #pragma unroll
        for (int j = 0; j < 8; ++j)
          acc[i][j] = fmaf(ar[i], br[j], acc[i][j]);
    }
    __syncthreads();
  }

  #pragma unroll
  for (int i = 0; i < 4; ++i) {
    int row = m0 + ty * 4 + i;
    float bb = bias[row];
    float4 o0, o1;
    o0.x = fmaxf(acc[i][0] + bb, 0.f);
    o0.y = fmaxf(acc[i][1] + bb, 0.f);
    o0.z = fmaxf(acc[i][2] + bb, 0.f);
    o0.w = fmaxf(acc[i][3] + bb, 0.f);
    o1.x = fmaxf(acc[i][4] + bb, 0.f);
    o1.y = fmaxf(acc[i][5] + bb, 0.f);
    o1.z = fmaxf(acc[i][6] + bb, 0.f);
    o1.w = fmaxf(acc[i][7] + bb, 0.f);
    *(float4*)&C[coff + (long)row * Nt + n0 + tx * 8] = o0;
    *(float4*)&C[coff + (long)row * Nt + n0 + tx * 8 + 4] = o1;
  }
}

// ---------------- heads: mu (normalized) + logvar ----------------
__global__ __launch_bounds__(256) void heads_kernel(
    const float* __restrict__ h2, const float* __restrict__ wm,
    const float* __restrict__ bm, const float* __restrict__ wv,
    const float* __restrict__ bv, float* __restrict__ out_mu,
    float* __restrict__ out_lv) {
  __shared__ float s_wm[8 * 256];
  __shared__ float s_wv[4 * 256];
  const int tid = threadIdx.x;
  for (int i = tid; i < 2048; i += 256) s_wm[i] = wm[i];
  for (int i = tid; i < 1024; i += 256) s_wv[i] = wv[i];
  __syncthreads();
  const int b = blockIdx.y;
  const int t = blockIdx.x * 256 + tid;
  float am[8] = {0, 0, 0, 0, 0, 0, 0, 0};
  float av_[4] = {0, 0, 0, 0};
  const float* hp = h2 + (long)b * H_ * T_ + t;
  for (int h = 0; h < 256; ++h) {
    float v = hp[(long)h * T_];
    #pragma unroll
    for (int o = 0; o < 8; ++o) am[o] += s_wm[o * 256 + h] * v;
    #pragma unroll
    for (int o = 0; o < 4; ++o) av_[o] += s_wv[o * 256 + h] * v;
  }
  const long bt = (long)b * T_ + t;
  #pragma unroll
  for (int ed = 0; ed < 4; ++ed) {
    float m0 = am[ed * 2] + bm[ed * 2];
    float m1 = am[ed * 2 + 1] + bm[ed * 2 + 1];
    float inv = 1.f / sqrtf(m0 * m0 + m1 * m1);
    out_mu[bt * 8 + ed * 2] = m0 * inv;
    out_mu[bt * 8 + ed * 2 + 1] = m1 * inv;
    out_lv[bt * 4 + ed] = av_[ed] + bv[ed];
  }
}

// ---------------- responses: bump basis + ensemble readout ----------------
__global__ __launch_bounds__(256) void resp_kernel(
    const float* __restrict__ z, const float* __restrict__ rf,
    const float* __restrict__ ew, const float* __restrict__ fs,
    const float* __restrict__ ltw, float* __restrict__ out) {
  __shared__ float s_sin[64][4];
  __shared__ float s_cos[64][4];
  __shared__ float s_w[64][2];
  const int tid = threadIdx.x;
  const int tc = blockIdx.x;
  const int nc = blockIdx.y;
  const int b = blockIdx.z;
  {
    int nl = tid >> 2, ed = tid & 3;
    float a = rf[(nc * 64 + nl) * 4 + ed];
    s_sin[nl][ed] = sinf(a);
    s_cos[nl][ed] = cosf(a);
  }
  if (tid < 64) {
    int n = nc * 64 + tid;
    float e0 = ew[n * 2], e1 = ew[n * 2 + 1];
    float m = fmaxf(e0, e1);
    float x0 = expf(e0 - m), x1 = expf(e1 - m);
    float sc = expf(fs[n]) / (x0 + x1);
    s_w[tid][0] = x0 * sc;
    s_w[tid][1] = x1 * sc;
  }
  __syncthreads();
  const int t = tc * 256 + tid;
  const float inv_tw = expf(-ltw[0]);
  float4 zv = *(const float4*)&z[((long)b * T_ + t) * 4];
  float sz0 = sinf(zv.x), cz0 = cosf(zv.x);
  float sz1 = sinf(zv.y), cz1 = cosf(zv.y);
  float sz2 = sinf(zv.z), cz2 = cosf(zv.z);
  float sz3 = sinf(zv.w), cz3 = cosf(zv.w);
  float* op = out + (long)b * N_ * T_ + (long)(nc * 64) * T_ + t;
  #pragma unroll 4
  for (int nl = 0; nl < 64; ++nl) {
    float dot0 = sz0 * s_sin[nl][0] + cz0 * s_cos[nl][0] +
                 sz1 * s_sin[nl][1] + cz1 * s_cos[nl][1];
    float dot1 = sz2 * s_sin[nl][2] + cz2 * s_cos[nl][2] +
                 sz3 * s_sin[nl][3] + cz3 * s_cos[nl][3];
    float r0 = __expf((2.f * dot0 - 4.f) * inv_tw);
    float r1 = __expf((2.f * dot1 - 4.f) * inv_tw);
    op[(long)nl * T_] = s_w[nl][0] * r0 + s_w[nl][1] * r1;
  }
}

extern "C" void kernel_launch(void* const* d_in, const int* in_sizes, int n_in,
                              void* d_out, int out_size, void* d_ws, size_t ws_size,
                              hipStream_t stream) {
  const float* x   = (const float*)d_in[0];
  const float* z   = (const float*)d_in[1];
  const float* dww = (const float*)d_in[2];
  const float* dwb = (const float*)d_in[3];
  const float* w1  = (const float*)d_in[4];
  const float* b1  = (const float*)d_in[5];
  const float* w2  = (const float*)d_in[6];
  const float* b2  = (const float*)d_in[7];
  const float* wm  = (const float*)d_in[8];
  const float* bm  = (const float*)d_in[9];
  const float* wv  = (const float*)d_in[10];
  const float* bv  = (const float*)d_in[11];
  const float* rf  = (const float*)d_in[12];
  const float* ew  = (const float*)d_in[13];
  const float* fs  = (const float*)d_in[14];
  const float* ltw = (const float*)d_in[15];

  float* out = (float*)d_out;
  float* out_resp = out;                         // [B,N,T]  8388608
  float* out_z    = out + (size_t)B_ * N_ * T_;  // [B,T,2,2] 32768
  float* out_mu   = out_z + (size_t)B_ * T_ * 4; // [B,T,2,2,2] 65536
  float* out_lv   = out_mu + (size_t)B_ * T_ * 8;// [B,T,2,2] 32768

  // h0 staged in the (not-yet-written) responses output region: same size,
  // dead before resp_kernel runs (stream-ordered). d_ws holds h1+h2 (16.8MB).
  float* h0 = out_resp;
  float* ws = (float*)d_ws;
  float* h1 = ws;                            // B*H*T
  float* h2 = ws + (size_t)B_ * H_ * T_;     // B*H*T

  dwconv_kernel<<<dim3(T_ / 256, N_, B_), 256, 0, stream>>>(x, dww, dwb, h0);
  gemm_bias_relu<<<dim3(T_ / BN, H_ / BM, B_), 256, 0, stream>>>(
      w1, h0, b1, h1, H_, N_, T_);
  gemm_bias_relu<<<dim3(T_ / BN, H_ / BM, B_), 256, 0, stream>>>(
      w2, h1, b2, h2, H_, H_, T_);
  heads_kernel<<<dim3(T_ / 256, B_), 256, 0, stream>>>(
      h2, wm, bm, wv, bv, out_mu, out_lv);
  hipMemcpyAsync(out_z, z, sizeof(float) * (size_t)B_ * T_ * 4,
                 hipMemcpyDeviceToDevice, stream);
  resp_kernel<<<dim3(T_ / 256, N_ / 64, B_), 256, 0, stream>>>(
      z, rf, ew, fs, ltw, out_resp);
}

// Round 2
// 197.268 us; speedup vs baseline: 1.4484x; 1.4484x over previous
//
#include <hip/hip_runtime.h>
#include <hip/hip_bf16.h>

#define B_ 2
#define N_ 1024
#define T_ 4096
#define H_ 256
#define ROWS_ 8192  // B*T

typedef float f32x4 __attribute__((ext_vector_type(4)));
typedef __bf16 bf16x8 __attribute__((ext_vector_type(8)));

__device__ __forceinline__ void gl16(const void* g, void* l) {
  __builtin_amdgcn_global_load_lds(
      (const __attribute__((address_space(1))) void*)g,
      (__attribute__((address_space(3))) void*)l, 16, 0, 0);
}

// ---------------- weight fp32 -> bf16 hi/lo split ----------------
__global__ __launch_bounds__(256) void cvt_split(
    const float* __restrict__ w1, const float* __restrict__ w2,
    __bf16* __restrict__ w1h, __bf16* __restrict__ w1l,
    __bf16* __restrict__ w2h, __bf16* __restrict__ w2l) {
  int i = blockIdx.x * 256 + threadIdx.x;
  if (i < 262144) {
    float v = w1[i];
    __bf16 h = (__bf16)v;
    w1h[i] = h;
    w1l[i] = (__bf16)(v - (float)h);
  } else {
    int j = i - 262144;
    float v = w2[j];
    __bf16 h = (__bf16)v;
    w2h[j] = h;
    w2l[j] = (__bf16)(v - (float)h);
  }
}

// ---------------- depthwise conv1d -> t-major h0 (hi/lo bf16) ----------------
__global__ __launch_bounds__(256) void dwconv_t(
    const float* __restrict__ x, const float* __restrict__ w,
    const float* __restrict__ bias, __bf16* __restrict__ h0h,
    __bf16* __restrict__ h0l) {
  __shared__ float xs[64][73];
  const int tid = threadIdx.x;
  const int t0 = blockIdx.x * 64;
  const int n0 = blockIdx.y * 64;
  const int b = blockIdx.z;
  for (int i = tid; i < 64 * 72; i += 256) {
    int rr = i / 72, cc = i % 72;
    int tt = t0 - 4 + cc;
    xs[rr][cc] = (tt >= 0 && tt < T_) ? x[((size_t)(b * N_ + n0 + rr)) * T_ + tt] : 0.f;
  }
  __syncthreads();
  const int nl = tid & 63;
  const int tg = tid >> 6;
  float wr[9];
  #pragma unroll
  for (int k = 0; k < 9; ++k) wr[k] = w[(n0 + nl) * 9 + k];
  const float bb = bias[n0 + nl];
  for (int j = 0; j < 16; ++j) {
    int tl = tg * 16 + j;
    float acc = bb;
    #pragma unroll
    for (int k = 0; k < 9; ++k) acc = fmaf(xs[nl][tl + k], wr[k], acc);
    size_t o = ((size_t)b * T_ + t0 + tl) * N_ + n0 + nl;
    __bf16 h = (__bf16)acc;
    h0h[o] = h;
    h0l[o] = (__bf16)(acc - (float)h);
  }
}

// ---------------- 3-pass split-bf16 MFMA GEMM ----------------
// O[row, g] = act( sum_k A[row,k]*W[g,k] + bias[g] ),  A:[8192,K], W:[256,K]
// tile 128 rows x 64 g, 4 waves (2x2), wave 64x32, frags 4x2, BK=32
__global__ __launch_bounds__(256) void gemm3p(
    const __bf16* __restrict__ Ah, const __bf16* __restrict__ Al,
    const __bf16* __restrict__ Wh, const __bf16* __restrict__ Wl,
    const float* __restrict__ bias, __bf16* __restrict__ Oh,
    __bf16* __restrict__ Ol, int K, int relu) {
  __shared__ __bf16 As[2][2][128 * 32];  // [buf][hi/lo]
  __shared__ __bf16 Ws[2][2][64 * 32];
  const int tid = threadIdx.x;
  // XCD-chunked swizzle: 256 blocks, 8 XCDs -> the 4 g-blocks of a t-tile
  // plus 8 t-tiles land on one XCD (A-tile stays in that XCD's L2).
  int orig = blockIdx.y * 4 + blockIdx.x;
  int rm = (orig & 7) * 32 + (orig >> 3);
  const int g0 = (rm & 3) * 64;
  const int row0 = (rm >> 2) * 128;

  const int sr = tid >> 2;  // staging row 0..63
  const int sl = tid & 3;   // 16B chunk within 64B row
  const size_t a_off0 = (size_t)(row0 + sr) * K + sl * 8;
  const size_t a_off1 = (size_t)(row0 + 64 + sr) * K + sl * 8;
  const size_t w_off = (size_t)(g0 + sr) * K + sl * 8;

  const int lane = tid & 63;
  const int wid = tid >> 6;
  const int wrr = (wid >> 1) * 64;  // wave t-offset
  const int wcc = (wid & 1) * 32;   // wave g-offset
  const int lr = lane & 15;
  const int ls = lane >> 4;

  f32x4 acc[4][2];
  #pragma unroll
  for (int i = 0; i < 4; ++i)
    #pragma unroll
    for (int j = 0; j < 2; ++j) acc[i][j] = (f32x4)0.f;

  auto STAGE = [&](int buf, int k0) {
    gl16(Ah + a_off0 + k0, &As[buf][0][tid * 8]);
    gl16(Ah + a_off1 + k0, &As[buf][0][(tid + 256) * 8]);
    gl16(Al + a_off0 + k0, &As[buf][1][tid * 8]);
    gl16(Al + a_off1 + k0, &As[buf][1][(tid + 256) * 8]);
    gl16(Wh + w_off + k0, &Ws[buf][0][tid * 8]);
    gl16(Wl + w_off + k0, &Ws[buf][1][tid * 8]);
  };

  const int nk = K >> 5;
  STAGE(0, 0);
  __syncthreads();  // compiler drains vmcnt before s_barrier
  for (int kt = 0; kt < nk; ++kt) {
    const int cur = kt & 1;
    if (kt + 1 < nk) STAGE(cur ^ 1, (kt + 1) << 5);
    bf16x8 ah[4], al[4], wh[2], wl[2];
    #pragma unroll
    for (int mi = 0; mi < 4; ++mi) {
      int r = wrr + mi * 16 + lr;
      ah[mi] = *(const bf16x8*)&As[cur][0][r * 32 + ls * 8];
      al[mi] = *(const bf16x8*)&As[cur][1][r * 32 + ls * 8];
    }
    #pragma unroll
    for (int ni = 0; ni < 2; ++ni) {
      int r = wcc + ni * 16 + lr;
      wh[ni] = *(const bf16x8*)&Ws[cur][0][r * 32 + ls * 8];
      wl[ni] = *(const bf16x8*)&Ws[cur][1][r * 32 + ls * 8];
    }
    #pragma unroll
    for (int mi = 0; mi < 4; ++mi)
      #pragma unroll
      for (int ni = 0; ni < 2; ++ni) {
        acc[mi][ni] = __builtin_amdgcn_mfma_f32_16x16x32_bf16(ah[mi], wh[ni], acc[mi][ni], 0, 0, 0);
        acc[mi][ni] = __builtin_amdgcn_mfma_f32_16x16x32_bf16(ah[mi], wl[ni], acc[mi][ni], 0, 0, 0);
        acc[mi][ni] = __builtin_amdgcn_mfma_f32_16x16x32_bf16(al[mi], wh[ni], acc[mi][ni], 0, 0, 0);
      }
    __syncthreads();
  }

  // epilogue: C/D layout col=lane&15, row=(lane>>4)*4+reg
  #pragma unroll
  for (int ni = 0; ni < 2; ++ni) {
    const int g = g0 + wcc + ni * 16 + lr;
    const float bb = bias[g];
    #pragma unroll
    for (int mi = 0; mi < 4; ++mi)
      #pragma unroll
      for (int reg = 0; reg < 4; ++reg) {
        int t = row0 + wrr + mi * 16 + ls * 4 + reg;
        float v = acc[mi][ni][reg] + bb;
        if (relu) v = fmaxf(v, 0.f);
        __bf16 h = (__bf16)v;
        Oh[(size_t)t * H_ + g] = h;
        Ol[(size_t)t * H_ + g] = (__bf16)(v - (float)h);
      }
  }
}

// ---------------- heads: mu (normalized) + logvar ----------------
__global__ __launch_bounds__(256) void heads_t(
    const __bf16* __restrict__ h2h, const __bf16* __restrict__ h2l,
    const float* __restrict__ wm, const float* __restrict__ bm,
    const float* __restrict__ wv, const float* __restrict__ bv,
    float* __restrict__ out_mu, float* __restrict__ out_lv) {
  __shared__ float sw[12][256];  // 0..7 wm, 8..11 wv
  const int tid = threadIdx.x;
  for (int i = tid; i < 8 * 256; i += 256) sw[i >> 8][i & 255] = wm[i];
  for (int i = tid; i < 4 * 256; i += 256) sw[8 + (i >> 8)][i & 255] = wv[i];
  __syncthreads();
  const int tq = tid & 3;
  const int tl = tid >> 2;
  const size_t row = blockIdx.x * 64 + tl;
  float s[12];
  #pragma unroll
  for (int o = 0; o < 12; ++o) s[o] = 0.f;
  for (int j = 0; j < 8; ++j) {
    int jj = (j + tq * 2) & 7;  // phase rotate to dodge LDS bank aliasing
    int k0 = tq * 64 + jj * 8;
    bf16x8 vh = *(const bf16x8*)&h2h[row * 256 + k0];
    bf16x8 vl = *(const bf16x8*)&h2l[row * 256 + k0];
    #pragma unroll
    for (int e = 0; e < 8; ++e) {
      float v = (float)vh[e] + (float)vl[e];
      #pragma unroll
      for (int o = 0; o < 12; ++o) s[o] = fmaf(sw[o][k0 + e], v, s[o]);
    }
  }
  #pragma unroll
  for (int o = 0; o < 12; ++o) {
    s[o] += __shfl_xor(s[o], 1);
    s[o] += __shfl_xor(s[o], 2);
  }
  if (tq == 0) {
    float4 m01, m23;
    float mm[8];
    #pragma unroll
    for (int ed = 0; ed < 4; ++ed) {
      float m0 = s[ed * 2] + bm[ed * 2];
      float m1 = s[ed * 2 + 1] + bm[ed * 2 + 1];
      float inv = 1.f / sqrtf(m0 * m0 + m1 * m1);
      mm[ed * 2] = m0 * inv;
      mm[ed * 2 + 1] = m1 * inv;
    }
    m01 = make_float4(mm[0], mm[1], mm[2], mm[3]);
    m23 = make_float4(mm[4], mm[5], mm[6], mm[7]);
    *(float4*)&out_mu[row * 8] = m01;
    *(float4*)&out_mu[row * 8 + 4] = m23;
  } else if (tq == 1) {
    float4 lv = make_float4(s[8] + bv[0], s[9] + bv[1], s[10] + bv[2], s[11] + bv[3]);
    *(float4*)&out_lv[row * 4] = lv;
  }
}

// ---------------- responses + z copy ----------------
__global__ __launch_bounds__(256) void resp_kernel(
    const float* __restrict__ z, const float* __restrict__ rf,
    const float* __restrict__ ew, const float* __restrict__ fs,
    const float* __restrict__ ltw, float* __restrict__ out,
    float* __restrict__ out_z) {
  __shared__ float s_sin[64][4];
  __shared__ float s_cos[64][4];
  __shared__ float s_w[64][2];
  const int tid = threadIdx.x;
  const int tc = blockIdx.x;
  const int nc = blockIdx.y;
  const int b = blockIdx.z;
  {
    int nl = tid >> 2, ed = tid & 3;
    float a = rf[(nc * 64 + nl) * 4 + ed];
    s_sin[nl][ed] = sinf(a);
    s_cos[nl][ed] = cosf(a);
  }
  if (tid < 64) {
    int n = nc * 64 + tid;
    float e0 = ew[n * 2], e1 = ew[n * 2 + 1];
    float m = fmaxf(e0, e1);
    float x0 = expf(e0 - m), x1 = expf(e1 - m);
    float sc = expf(fs[n]) / (x0 + x1);
    s_w[tid][0] = x0 * sc;
    s_w[tid][1] = x1 * sc;
  }
  __syncthreads();
  const int t = tc * 256 + tid;
  const float inv_tw = expf(-ltw[0]);
  float4 zv = *(const float4*)&z[((size_t)b * T_ + t) * 4];
  if (nc == 0) *(float4*)&out_z[((size_t)b * T_ + t) * 4] = zv;
  float sz0 = sinf(zv.x), cz0 = cosf(zv.x);
  float sz1 = sinf(zv.y), cz1 = cosf(zv.y);
  float sz2 = sinf(zv.z), cz2 = cosf(zv.z);
  float sz3 = sinf(zv.w), cz3 = cosf(zv.w);
  float* op = out + (size_t)b * N_ * T_ + (size_t)(nc * 64) * T_ + t;
  #pragma unroll 4
  for (int nl = 0; nl < 64; ++nl) {
    float dot0 = sz0 * s_sin[nl][0] + cz0 * s_cos[nl][0] +
                 sz1 * s_sin[nl][1] + cz1 * s_cos[nl][1];
    float dot1 = sz2 * s_sin[nl][2] + cz2 * s_cos[nl][2] +
                 sz3 * s_sin[nl][3] + cz3 * s_cos[nl][3];
    float r0 = __expf((2.f * dot0 - 4.f) * inv_tw);
    float r1 = __expf((2.f * dot1 - 4.f) * inv_tw);
    op[(size_t)nl * T_] = s_w[nl][0] * r0 + s_w[nl][1] * r1;
  }
}

extern "C" void kernel_launch(void* const* d_in, const int* in_sizes, int n_in,
                              void* d_out, int out_size, void* d_ws, size_t ws_size,
                              hipStream_t stream) {
  const float* x   = (const float*)d_in[0];
  const float* z   = (const float*)d_in[1];
  const float* dww = (const float*)d_in[2];
  const float* dwb = (const float*)d_in[3];
  const float* w1  = (const float*)d_in[4];
  const float* b1  = (const float*)d_in[5];
  const float* w2  = (const float*)d_in[6];
  const float* b2  = (const float*)d_in[7];
  const float* wm  = (const float*)d_in[8];
  const float* bm  = (const float*)d_in[9];
  const float* wv  = (const float*)d_in[10];
  const float* bv  = (const float*)d_in[11];
  const float* rf  = (const float*)d_in[12];
  const float* ew  = (const float*)d_in[13];
  const float* fs  = (const float*)d_in[14];
  const float* ltw = (const float*)d_in[15];

  float* out = (float*)d_out;
  float* out_resp = out;                          // [B,N,T]   8388608 f32
  float* out_z    = out + (size_t)B_ * N_ * T_;   // [B,T,2,2]
  float* out_mu   = out_z + (size_t)B_ * T_ * 4;  // [B,T,2,2,2]
  float* out_lv   = out_mu + (size_t)B_ * T_ * 8; // [B,T,2,2]

  // h0 hi/lo planes live in the responses output region (exactly 33.55MB),
  // dead before resp_kernel runs (stream-ordered).
  __bf16* h0h = (__bf16*)out_resp;
  __bf16* h0l = h0h + (size_t)ROWS_ * N_;

  __bf16* p = (__bf16*)d_ws;
  __bf16* w1h = p; p += 262144;
  __bf16* w1l = p; p += 262144;
  __bf16* w2h = p; p += 65536;
  __bf16* w2l = p; p += 65536;
  __bf16* h1h = p; p += (size_t)ROWS_ * H_;
  __bf16* h1l = p; p += (size_t)ROWS_ * H_;
  __bf16* h2h = p; p += (size_t)ROWS_ * H_;
  __bf16* h2l = p; p += (size_t)ROWS_ * H_;

  cvt_split<<<1280, 256, 0, stream>>>(w1, w2, w1h, w1l, w2h, w2l);
  dwconv_t<<<dim3(T_ / 64, N_ / 64, B_), 256, 0, stream>>>(x, dww, dwb, h0h, h0l);
  gemm3p<<<dim3(4, ROWS_ / 128, 1), 256, 0, stream>>>(
      h0h, h0l, w1h, w1l, b1, h1h, h1l, N_, 1);
  gemm3p<<<dim3(4, ROWS_ / 128, 1), 256, 0, stream>>>(
      h1h, h1l, w2h, w2l, b2, h2h, h2l, H_, 1);
  heads_t<<<dim3(ROWS_ / 64), 256, 0, stream>>>(
      h2h, h2l, wm, bm, wv, bv, out_mu, out_lv);
  resp_kernel<<<dim3(T_ / 256, N_ / 64, B_), 256, 0, stream>>>(
      z, rf, ew, fs, ltw, out_resp, out_z);
}

// Round 3
// 183.022 us; speedup vs baseline: 1.5611x; 1.0778x over previous
//
#include <hip/hip_runtime.h>
#include <hip/hip_bf16.h>

#define B_ 2
#define N_ 1024
#define T_ 4096
#define H_ 256
#define ROWS_ 8192  // B*T

typedef float f32x4 __attribute__((ext_vector_type(4)));
typedef __bf16 bf16x8 __attribute__((ext_vector_type(8)));

__device__ __forceinline__ void gl16(const void* g, void* l) {
  __builtin_amdgcn_global_load_lds(
      (const __attribute__((address_space(1))) void*)g,
      (__attribute__((address_space(3))) void*)l, 16, 0, 0);
}

// ---------------- weight fp32 -> bf16 hi/lo split ----------------
__global__ __launch_bounds__(256) void cvt_split(
    const float* __restrict__ w1, const float* __restrict__ w2,
    __bf16* __restrict__ w1h, __bf16* __restrict__ w1l,
    __bf16* __restrict__ w2h, __bf16* __restrict__ w2l) {
  int i = blockIdx.x * 256 + threadIdx.x;
  if (i < 262144) {
    float v = w1[i];
    __bf16 h = (__bf16)v;
    w1h[i] = h;
    w1l[i] = (__bf16)(v - (float)h);
  } else {
    int j = i - 262144;
    float v = w2[j];
    __bf16 h = (__bf16)v;
    w2h[j] = h;
    w2l[j] = (__bf16)(v - (float)h);
  }
}

// ---------------- depthwise conv1d -> t-major h0 (hi/lo bf16) ----------------
// block: 64 n x 64 t. Thread owns one n-row, 16 t's; taps come from a
// register window (6x ds_read_b128), not scalar LDS reads.
__global__ __launch_bounds__(256) void dwconv_t(
    const float* __restrict__ x, const float* __restrict__ w,
    const float* __restrict__ bias, __bf16* __restrict__ h0h,
    __bf16* __restrict__ h0l) {
  __shared__ float xs[64][76];  // 72 used; stride 76 words tiles 8 bank-quads
  const int tid = threadIdx.x;
  const int t0 = blockIdx.x * 64;
  const int n0 = blockIdx.y * 64;
  const int b = blockIdx.z;
  for (int i = tid; i < 64 * 72; i += 256) {
    int rr = i / 72, cc = i % 72;
    int tt = t0 - 4 + cc;
    xs[rr][cc] = (tt >= 0 && tt < T_) ? x[((size_t)(b * N_ + n0 + rr)) * T_ + tt] : 0.f;
  }
  const int nl = tid & 63;   // lane == n-row (tg uniform per wave)
  const int tg = tid >> 6;
  float wr[9];
  #pragma unroll
  for (int k = 0; k < 9; ++k) wr[k] = w[(n0 + nl) * 9 + k];
  const float bb = bias[n0 + nl];
  __syncthreads();
  // register window: taps for t in [tg*16, tg*16+16) live at halo cols
  // [tg*16, tg*16+24)
  float win[24];
  #pragma unroll
  for (int c = 0; c < 6; ++c)
    *(f32x4*)&win[c * 4] = *(const f32x4*)&xs[nl][tg * 16 + c * 4];
  const size_t obase = ((size_t)b * T_ + t0 + tg * 16) * N_ + n0 + nl;
  #pragma unroll
  for (int j = 0; j < 16; ++j) {
    float acc = bb;
    #pragma unroll
    for (int k = 0; k < 9; ++k) acc = fmaf(win[j + k], wr[k], acc);
    __bf16 h = (__bf16)acc;
    h0h[obase + (size_t)j * N_] = h;
    h0l[obase + (size_t)j * N_] = (__bf16)(acc - (float)h);
  }
}

// ---------------- 3-pass split-bf16 MFMA GEMM ----------------
// O[row,g] = act( sum_k A[row,k]*W[g,k] + bias[g] ), A:[8192,K], W:[256,K]
// tile 64 rows x 64 g, 4 waves (2x2), BK=32, grid 512 -> 2 blocks/CU.
__global__ __launch_bounds__(256) void gemm3p(
    const __bf16* __restrict__ Ah, const __bf16* __restrict__ Al,
    const __bf16* __restrict__ Wh, const __bf16* __restrict__ Wl,
    const float* __restrict__ bias, __bf16* __restrict__ Oh,
    __bf16* __restrict__ Ol, int K, int relu) {
  __shared__ __bf16 As[2][2][64 * 32];  // [buf][hi/lo], 4KB each
  __shared__ __bf16 Ws[2][2][64 * 32];
  const int tid = threadIdx.x;
  // XCD-chunked swizzle over 512 blocks: each XCD gets 16 row-tiles x 4
  // g-tiles, g fastest -> A-tile reuse lands in one XCD's L2.
  const int orig = blockIdx.x;
  const int rm = (orig & 7) * 64 + (orig >> 3);
  const int g0 = (rm & 3) * 64;
  const int row0 = (rm >> 2) * 64;

  const int sr = tid >> 2;                 // staging row 0..63
  const int sl = tid & 3;                  // 16B slot in 64B row
  const int ssl = sl ^ ((sr >> 1) & 3);    // XOR-swizzled source k-chunk
  const size_t a_off = (size_t)(row0 + sr) * K + ssl * 8;
  const size_t w_off = (size_t)(g0 + sr) * K + ssl * 8;

  const int lane = tid & 63;
  const int wid = tid >> 6;
  const int wrr = (wid >> 1) * 32;  // wave row-offset
  const int wcc = (wid & 1) * 32;   // wave g-offset
  const int lr = lane & 15;
  const int ls = lane >> 4;

  f32x4 acc[2][2];
  #pragma unroll
  for (int i = 0; i < 2; ++i)
    #pragma unroll
    for (int j = 0; j < 2; ++j) acc[i][j] = (f32x4)0.f;

  auto STAGE = [&](int buf, int k0) {
    gl16(Ah + a_off + k0, &As[buf][0][tid * 8]);
    gl16(Al + a_off + k0, &As[buf][1][tid * 8]);
    gl16(Wh + w_off + k0, &Ws[buf][0][tid * 8]);
    gl16(Wl + w_off + k0, &Ws[buf][1][tid * 8]);
  };

  // swizzled frag read address: row r, k-slice ls
  auto FADDR = [&](int r) { return r * 32 + (ls ^ ((r >> 1) & 3)) * 8; };

  const int nk = K >> 5;
  STAGE(0, 0);
  __syncthreads();
  for (int kt = 0; kt < nk; ++kt) {
    const int cur = kt & 1;
    if (kt + 1 < nk) STAGE(cur ^ 1, (kt + 1) << 5);
    bf16x8 ah[2], al[2], wh[2], wl[2];
    #pragma unroll
    for (int mi = 0; mi < 2; ++mi) {
      int a = FADDR(wrr + mi * 16 + lr);
      ah[mi] = *(const bf16x8*)&As[cur][0][a];
      al[mi] = *(const bf16x8*)&As[cur][1][a];
    }
    #pragma unroll
    for (int ni = 0; ni < 2; ++ni) {
      int a = FADDR(wcc + ni * 16 + lr);
      wh[ni] = *(const bf16x8*)&Ws[cur][0][a];
      wl[ni] = *(const bf16x8*)&Ws[cur][1][a];
    }
    #pragma unroll
    for (int mi = 0; mi < 2; ++mi)
      #pragma unroll
      for (int ni = 0; ni < 2; ++ni) {
        acc[mi][ni] = __builtin_amdgcn_mfma_f32_16x16x32_bf16(ah[mi], wh[ni], acc[mi][ni], 0, 0, 0);
        acc[mi][ni] = __builtin_amdgcn_mfma_f32_16x16x32_bf16(ah[mi], wl[ni], acc[mi][ni], 0, 0, 0);
        acc[mi][ni] = __builtin_amdgcn_mfma_f32_16x16x32_bf16(al[mi], wh[ni], acc[mi][ni], 0, 0, 0);
      }
    __syncthreads();
  }

  // epilogue: C/D layout col=lane&15, row=(lane>>4)*4+reg
  #pragma unroll
  for (int ni = 0; ni < 2; ++ni) {
    const int g = g0 + wcc + ni * 16 + lr;
    const float bb = bias[g];
    #pragma unroll
    for (int mi = 0; mi < 2; ++mi)
      #pragma unroll
      for (int reg = 0; reg < 4; ++reg) {
        int t = row0 + wrr + mi * 16 + ls * 4 + reg;
        float v = acc[mi][ni][reg] + bb;
        if (relu) v = fmaxf(v, 0.f);
        __bf16 h = (__bf16)v;
        Oh[(size_t)t * H_ + g] = h;
        Ol[(size_t)t * H_ + g] = (__bf16)(v - (float)h);
      }
  }
}

// ---------------- heads: mu (normalized) + logvar ----------------
__global__ __launch_bounds__(256) void heads_t(
    const __bf16* __restrict__ h2h, const __bf16* __restrict__ h2l,
    const float* __restrict__ wm, const float* __restrict__ bm,
    const float* __restrict__ wv, const float* __restrict__ bv,
    float* __restrict__ out_mu, float* __restrict__ out_lv) {
  __shared__ float sw[12][256];  // 0..7 wm, 8..11 wv
  const int tid = threadIdx.x;
  for (int i = tid; i < 8 * 256; i += 256) sw[i >> 8][i & 255] = wm[i];
  for (int i = tid; i < 4 * 256; i += 256) sw[8 + (i >> 8)][i & 255] = wv[i];
  __syncthreads();
  const int tq = tid & 3;
  const int tl = tid >> 2;
  const size_t row = blockIdx.x * 64 + tl;
  float s[12];
  #pragma unroll
  for (int o = 0; o < 12; ++o) s[o] = 0.f;
  for (int j = 0; j < 8; ++j) {
    int jj = (j + tq * 2) & 7;  // phase rotate to dodge LDS bank aliasing
    int k0 = tq * 64 + jj * 8;
    bf16x8 vh = *(const bf16x8*)&h2h[row * 256 + k0];
    bf16x8 vl = *(const bf16x8*)&h2l[row * 256 + k0];
    #pragma unroll
    for (int e = 0; e < 8; ++e) {
      float v = (float)vh[e] + (float)vl[e];
      #pragma unroll
      for (int o = 0; o < 12; ++o) s[o] = fmaf(sw[o][k0 + e], v, s[o]);
    }
  }
  #pragma unroll
  for (int o = 0; o < 12; ++o) {
    s[o] += __shfl_xor(s[o], 1);
    s[o] += __shfl_xor(s[o], 2);
  }
  if (tq == 0) {
    float mm[8];
    #pragma unroll
    for (int ed = 0; ed < 4; ++ed) {
      float m0 = s[ed * 2] + bm[ed * 2];
      float m1 = s[ed * 2 + 1] + bm[ed * 2 + 1];
      float inv = 1.f / sqrtf(m0 * m0 + m1 * m1);
      mm[ed * 2] = m0 * inv;
      mm[ed * 2 + 1] = m1 * inv;
    }
    *(float4*)&out_mu[row * 8] = make_float4(mm[0], mm[1], mm[2], mm[3]);
    *(float4*)&out_mu[row * 8 + 4] = make_float4(mm[4], mm[5], mm[6], mm[7]);
  } else if (tq == 1) {
    *(float4*)&out_lv[row * 4] =
        make_float4(s[8] + bv[0], s[9] + bv[1], s[10] + bv[2], s[11] + bv[3]);
  }
}

// ---------------- responses + z copy ----------------
__global__ __launch_bounds__(256) void resp_kernel(
    const float* __restrict__ z, const float* __restrict__ rf,
    const float* __restrict__ ew, const float* __restrict__ fs,
    const float* __restrict__ ltw, float* __restrict__ out,
    float* __restrict__ out_z) {
  __shared__ float s_sin[64][4];
  __shared__ float s_cos[64][4];
  __shared__ float s_w[64][2];
  const int tid = threadIdx.x;
  const int tc = blockIdx.x;
  const int nc = blockIdx.y;
  const int b = blockIdx.z;
  {
    int nl = tid >> 2, ed = tid & 3;
    float a = rf[(nc * 64 + nl) * 4 + ed];
    s_sin[nl][ed] = sinf(a);
    s_cos[nl][ed] = cosf(a);
  }
  if (tid < 64) {
    int n = nc * 64 + tid;
    float e0 = ew[n * 2], e1 = ew[n * 2 + 1];
    float m = fmaxf(e0, e1);
    float x0 = expf(e0 - m), x1 = expf(e1 - m);
    float sc = expf(fs[n]) / (x0 + x1);
    s_w[tid][0] = x0 * sc;
    s_w[tid][1] = x1 * sc;
  }
  __syncthreads();
  const int t = tc * 256 + tid;
  const float inv_tw = expf(-ltw[0]);
  float4 zv = *(const float4*)&z[((size_t)b * T_ + t) * 4];
  if (nc == 0) *(float4*)&out_z[((size_t)b * T_ + t) * 4] = zv;
  float sz0 = sinf(zv.x), cz0 = cosf(zv.x);
  float sz1 = sinf(zv.y), cz1 = cosf(zv.y);
  float sz2 = sinf(zv.z), cz2 = cosf(zv.z);
  float sz3 = sinf(zv.w), cz3 = cosf(zv.w);
  float* op = out + (size_t)b * N_ * T_ + (size_t)(nc * 64) * T_ + t;
  #pragma unroll 4
  for (int nl = 0; nl < 64; ++nl) {
    float dot0 = sz0 * s_sin[nl][0] + cz0 * s_cos[nl][0] +
                 sz1 * s_sin[nl][1] + cz1 * s_cos[nl][1];
    float dot1 = sz2 * s_sin[nl][2] + cz2 * s_cos[nl][2] +
                 sz3 * s_sin[nl][3] + cz3 * s_cos[nl][3];
    float r0 = __expf((2.f * dot0 - 4.f) * inv_tw);
    float r1 = __expf((2.f * dot1 - 4.f) * inv_tw);
    op[(size_t)nl * T_] = s_w[nl][0] * r0 + s_w[nl][1] * r1;
  }
}

extern "C" void kernel_launch(void* const* d_in, const int* in_sizes, int n_in,
                              void* d_out, int out_size, void* d_ws, size_t ws_size,
                              hipStream_t stream) {
  const float* x   = (const float*)d_in[0];
  const float* z   = (const float*)d_in[1];
  const float* dww = (const float*)d_in[2];
  const float* dwb = (const float*)d_in[3];
  const float* w1  = (const float*)d_in[4];
  const float* b1  = (const float*)d_in[5];
  const float* w2  = (const float*)d_in[6];
  const float* b2  = (const float*)d_in[7];
  const float* wm  = (const float*)d_in[8];
  const float* bm  = (const float*)d_in[9];
  const float* wv  = (const float*)d_in[10];
  const float* bv  = (const float*)d_in[11];
  const float* rf  = (const float*)d_in[12];
  const float* ew  = (const float*)d_in[13];
  const float* fs  = (const float*)d_in[14];
  const float* ltw = (const float*)d_in[15];

  float* out = (float*)d_out;
  float* out_resp = out;                          // [B,N,T]
  float* out_z    = out + (size_t)B_ * N_ * T_;   // [B,T,2,2]
  float* out_mu   = out_z + (size_t)B_ * T_ * 4;  // [B,T,2,2,2]
  float* out_lv   = out_mu + (size_t)B_ * T_ * 8; // [B,T,2,2]

  // h0 hi/lo planes live in the responses output region (same 33.55MB),
  // dead before resp_kernel runs (stream-ordered).
  __bf16* h0h = (__bf16*)out_resp;
  __bf16* h0l = h0h + (size_t)ROWS_ * N_;

  __bf16* p = (__bf16*)d_ws;
  __bf16* w1h = p; p += 262144;
  __bf16* w1l = p; p += 262144;
  __bf16* w2h = p; p += 65536;
  __bf16* w2l = p; p += 65536;
  __bf16* h1h = p; p += (size_t)ROWS_ * H_;
  __bf16* h1l = p; p += (size_t)ROWS_ * H_;
  __bf16* h2h = p; p += (size_t)ROWS_ * H_;
  __bf16* h2l = p; p += (size_t)ROWS_ * H_;

  cvt_split<<<1280, 256, 0, stream>>>(w1, w2, w1h, w1l, w2h, w2l);
  dwconv_t<<<dim3(T_ / 64, N_ / 64, B_), 256, 0, stream>>>(x, dww, dwb, h0h, h0l);
  gemm3p<<<dim3(512), 256, 0, stream>>>(h0h, h0l, w1h, w1l, b1, h1h, h1l, N_, 1);
  gemm3p<<<dim3(512), 256, 0, stream>>>(h1h, h1l, w2h, w2l, b2, h2h, h2l, H_, 1);
  heads_t<<<dim3(ROWS_ / 64), 256, 0, stream>>>(
      h2h, h2l, wm, bm, wv, bv, out_mu, out_lv);
  resp_kernel<<<dim3(T_ / 256, N_ / 64, B_), 256, 0, stream>>>(
      z, rf, ew, fs, ltw, out_resp, out_z);
}